// Round 5
// baseline (3978.246 us; speedup 1.0000x reference)
//
#include <hip/hip_runtime.h>
#include <stdint.h>

// ActuatorPolicyNet: x[2048,512] -> LSTM(H=1024) -> fc1 -> fc2 -> mean head.
// Phase B: persistent LSTM, 128 wg x 512 thr, unit-per-wave, register-resident
// w_hh (waves_per_eu(2,2) => 256-VGPR budget; named float4 values pinned
// component-wise — vector-tied asm operands don't compile on gfx950), 16-B
// sentinel polls with s_sleep backoff, single barrier + double-buffered LDS.

#define T_SEQ 2048
#define H 1024
#define G4 4096
#define K_IN 512
#define SENT 0x7FC0DEADu  // NaN bit pattern; real h values are never NaN

__device__ __forceinline__ float sigmoidf_(float x) { return 1.0f / (1.0f + __expf(-x)); }
__device__ __forceinline__ float tanhf_(float x) { return 1.0f - 2.0f / (1.0f + __expf(2.0f * x)); }

// 16-B coherent poll load (reads at the device coherence point: sc0 sc1)
__device__ __forceinline__ uint4 poll_load16(const uint4* p) {
  uint4 v;
  asm volatile("global_load_dwordx4 %0, %1, off sc0 sc1\n\ts_waitcnt vmcnt(0)"
               : "=v"(v) : "v"(p) : "memory");
  return v;
}

// ---------------- init: h_hist[0] = h0, rows 1..2048 = sentinel ----------------
__global__ void init_k(const float* __restrict__ h0, float* __restrict__ h_hist) {
  int idx = blockIdx.x * blockDim.x + threadIdx.x;
  if (idx < H) {
    h_hist[idx] = h0[idx];
  } else if (idx < (T_SEQ + 1) * H) {
    ((unsigned*)h_hist)[idx] = SENT;
  }
}

// ---------------- generic fp32 GEMM: C = act(A[M,K] @ Bw[N,K]^T + b1 (+ b2)) ----------------
#define BM 64
#define BN 64
#define BK 32
#define LDT 68

template <bool RELU, bool HASB2>
__global__ __launch_bounds__(256) void gemm_bias_k(
    const float* __restrict__ A, const float* __restrict__ Bw,
    const float* __restrict__ b1, const float* __restrict__ b2,
    float* __restrict__ C, int M, int N, int K) {
  __shared__ float As[BK][LDT];
  __shared__ float Bs[BK][LDT];
  const int tid = threadIdx.x;
  const int m0 = blockIdx.y * BM;
  const int n0 = blockIdx.x * BN;
  const int tx = tid & 15, ty = tid >> 4;
  const int srow = tid >> 2;
  const int skq = tid & 3;

  float acc[4][4];
#pragma unroll
  for (int i = 0; i < 4; i++)
#pragma unroll
    for (int j = 0; j < 4; j++) acc[i][j] = 0.f;

  const float* Arow = A + (size_t)(m0 + srow) * K;
  const float* Brow = Bw + (size_t)(n0 + srow) * K;

  for (int k0 = 0; k0 < K; k0 += BK) {
    float4 a0 = *(const float4*)(Arow + k0 + skq * 8);
    float4 a1 = *(const float4*)(Arow + k0 + skq * 8 + 4);
    float4 c0_ = *(const float4*)(Brow + k0 + skq * 8);
    float4 c1_ = *(const float4*)(Brow + k0 + skq * 8 + 4);
    __syncthreads();
    const int kb = skq * 8;
    As[kb + 0][srow] = a0.x; As[kb + 1][srow] = a0.y; As[kb + 2][srow] = a0.z; As[kb + 3][srow] = a0.w;
    As[kb + 4][srow] = a1.x; As[kb + 5][srow] = a1.y; As[kb + 6][srow] = a1.z; As[kb + 7][srow] = a1.w;
    Bs[kb + 0][srow] = c0_.x; Bs[kb + 1][srow] = c0_.y; Bs[kb + 2][srow] = c0_.z; Bs[kb + 3][srow] = c0_.w;
    Bs[kb + 4][srow] = c1_.x; Bs[kb + 5][srow] = c1_.y; Bs[kb + 6][srow] = c1_.z; Bs[kb + 7][srow] = c1_.w;
    __syncthreads();
#pragma unroll
    for (int kk = 0; kk < BK; kk++) {
      float av[4], bv[4];
      *(float4*)av = *(const float4*)&As[kk][ty * 4];
      *(float4*)bv = *(const float4*)&Bs[kk][tx * 4];
#pragma unroll
      for (int i = 0; i < 4; i++)
#pragma unroll
        for (int j = 0; j < 4; j++) acc[i][j] = fmaf(av[i], bv[j], acc[i][j]);
    }
  }

  float bb[4];
#pragma unroll
  for (int j = 0; j < 4; j++) {
    bb[j] = b1[n0 + tx * 4 + j];
    if (HASB2) bb[j] += b2[n0 + tx * 4 + j];
  }
#pragma unroll
  for (int i = 0; i < 4; i++) {
    float4 o;
    float* op = (float*)&o;
#pragma unroll
    for (int j = 0; j < 4; j++) {
      float v = acc[i][j] + bb[j];
      op[j] = RELU ? fmaxf(v, 0.f) : v;
    }
    *(float4*)&C[(size_t)(m0 + ty * 4 + i) * N + n0 + tx * 4] = o;
  }
}

// ---------------- persistent LSTM recurrence ----------------
// 128 wgs x 512 thr (8 waves). wg owns 8 units; wave owns 1 unit.
// Lane = s*4+g (g=gate i,f,g,o; s=64-wide k-segment). Each lane holds
// w_hh[g*1024+unit][s*64..+64) in 16 named float4 values, pinned component-
// wise; waves_per_eu(2,2) caps occupancy so the 256-VGPR budget is free.
// Exchange: agent-scope atomic stores; 256 pollers/wg spin one dwordx4
// sc0/sc1 load each with s_sleep(1) backoff (data-is-the-flag).
#define NWG 128
#define NTHR 512
#define HPAD 68

#define PIN4(V) asm volatile("" : "+v"((V).x), "+v"((V).y), "+v"((V).z), "+v"((V).w))

__global__ __attribute__((amdgpu_waves_per_eu(2, 2))) __launch_bounds__(NTHR)
void lstm_k(
    const float* __restrict__ gx, const float* __restrict__ w_hh,
    const float* __restrict__ c0, float* __restrict__ h_hist,
    float* __restrict__ out) {
  unsigned* h_u = (unsigned*)h_hist;
  __shared__ float hbuf[2][16 * HPAD];
  const int tid = threadIdx.x;
  const int wg = blockIdx.x;
  const int wave = tid >> 6, lane = tid & 63;
  const int g = lane & 3;        // gate: 0=i 1=f 2=g 3=o
  const int s = lane >> 2;       // k-segment (0..15), 64 values each
  const int unit = wg * 8 + wave;
  const int grow = g * 1024 + unit;

  // preload weights into 16 named float4 SSA values (no array -> no alloca)
  const float* wp = w_hh + (size_t)grow * H + s * 64;
  float4 w0 = *(const float4*)(wp + 0),  w1 = *(const float4*)(wp + 4);
  float4 w2 = *(const float4*)(wp + 8),  w3 = *(const float4*)(wp + 12);
  float4 w4 = *(const float4*)(wp + 16), w5 = *(const float4*)(wp + 20);
  float4 w6 = *(const float4*)(wp + 24), w7 = *(const float4*)(wp + 28);
  float4 w8 = *(const float4*)(wp + 32), w9 = *(const float4*)(wp + 36);
  float4 wA = *(const float4*)(wp + 40), wB = *(const float4*)(wp + 44);
  float4 wC = *(const float4*)(wp + 48), wD = *(const float4*)(wp + 52);
  float4 wE = *(const float4*)(wp + 56), wF = *(const float4*)(wp + 60);
  // component-wise pins: force materialization, defeat remat (scalar operands
  // only — gfx950 inline asm can't tie vector registers)
  PIN4(w0); PIN4(w1); PIN4(w2); PIN4(w3);
  PIN4(w4); PIN4(w5); PIN4(w6); PIN4(w7);
  PIN4(w8); PIN4(w9); PIN4(wA); PIN4(wB);
  PIN4(wC); PIN4(wD); PIN4(wE); PIN4(wF);

  float c = c0[unit];  // meaningful in g==0 lanes only

  const bool poller = tid < 256;
  const int stage_idx = 4 * tid + (tid >> 4) * 4;  // padded LDS slot

  for (int t = 0; t < T_SEQ; t++) {
    const int buf = t & 1;
    // prefetch this step's gx so its latency overlaps the poll
    float gxv = gx[(size_t)t * G4 + grow];
    asm volatile("" : "+v"(gxv));

    if (poller) {
      const uint4* src = (const uint4*)(h_u + (size_t)t * H) + tid;
      uint4 v = poll_load16(src);
      while (v.x == SENT || v.y == SENT || v.z == SENT || v.w == SENT) {
        __builtin_amdgcn_s_sleep(1);  // ~64 cyc backoff: cut poll fabric storm
        v = poll_load16(src);
      }
      float4 f;
      f.x = __uint_as_float(v.x); f.y = __uint_as_float(v.y);
      f.z = __uint_as_float(v.z); f.w = __uint_as_float(v.w);
      *(float4*)&hbuf[buf][stage_idx] = f;
    }
    __syncthreads();  // single barrier per step (double-buffered hbuf)

    // 64 MACs, 4 accumulators, weights from named regs
    float acc0 = 0.f, acc1 = 0.f, acc2 = 0.f, acc3 = 0.f;
    const float* hs = &hbuf[buf][s * HPAD];
#define MAC(J, WV)                                  \
  {                                                 \
    float4 hv = *(const float4*)(hs + (J) * 4);     \
    acc0 = fmaf((WV).x, hv.x, acc0);                \
    acc1 = fmaf((WV).y, hv.y, acc1);                \
    acc2 = fmaf((WV).z, hv.z, acc2);                \
    acc3 = fmaf((WV).w, hv.w, acc3);                \
  }
    MAC(0, w0) MAC(1, w1) MAC(2, w2) MAC(3, w3)
    MAC(4, w4) MAC(5, w5) MAC(6, w6) MAC(7, w7)
    MAC(8, w8) MAC(9, w9) MAC(10, wA) MAC(11, wB)
    MAC(12, wC) MAC(13, wD) MAC(14, wE) MAC(15, wF)
#undef MAC
    float accv = (acc0 + acc1) + (acc2 + acc3);
    // reduce over the 16 k-segments (lane bits 2..5)
    accv += __shfl_xor(accv, 4);
    accv += __shfl_xor(accv, 8);
    accv += __shfl_xor(accv, 16);
    accv += __shfl_xor(accv, 32);
    float pre = accv + gxv;
    float act = (g == 2) ? tanhf_(pre) : sigmoidf_(pre);
    // gather gates (combination valid in g==0 lanes)
    float b1v = __shfl_xor(act, 1);
    float b2v = __shfl_xor(act, 2);
    float b3v = __shfl_xor(act, 3);
    c = fmaf(b1v, c, act * b2v);  // f*c + i*g   (g==0 lanes)
    float hn = b3v * tanhf_(c);   // o*tanh(c)
    if (lane == 0) {
      __hip_atomic_store(&h_u[(size_t)(t + 1) * H + unit], __float_as_uint(hn),
                         __ATOMIC_RELAXED, __HIP_MEMORY_SCOPE_AGENT);
      if (t == T_SEQ - 1) {
        out[16384 + unit] = hn;  // hT
        out[17408 + unit] = c;   // cT
      }
    }
  }
}

// ---------------- head: action_mean + log_std broadcast ----------------
__global__ __launch_bounds__(256) void head_k(
    const float* __restrict__ h2, const float* __restrict__ mean_w,
    const float* __restrict__ mean_b, const float* __restrict__ log_std,
    float* __restrict__ out) {
  const int t = blockIdx.x;
  const int tid = threadIdx.x;
  const int wave = tid >> 6, lane = tid & 63;  // wave = output index (OUT=4)
  const float* hr = h2 + (size_t)t * H;
  const float* wr = mean_w + (size_t)wave * H;
  float s = 0.f;
#pragma unroll
  for (int j = 0; j < 16; j++) s = fmaf(hr[lane + j * 64], wr[lane + j * 64], s);
#pragma unroll
  for (int off = 32; off > 0; off >>= 1) s += __shfl_down(s, off);
  if (lane == 0) out[t * 4 + wave] = s + mean_b[wave];
  if (tid < 4) out[8192 + t * 4 + tid] = log_std[tid];
}

extern "C" void kernel_launch(void* const* d_in, const int* in_sizes, int n_in,
                              void* d_out, int out_size, void* d_ws, size_t ws_size,
                              hipStream_t stream) {
  const float* x      = (const float*)d_in[0];
  const float* h0     = (const float*)d_in[1];
  const float* c0     = (const float*)d_in[2];
  const float* w_ih   = (const float*)d_in[3];
  const float* w_hh   = (const float*)d_in[4];
  const float* b_ih   = (const float*)d_in[5];
  const float* b_hh   = (const float*)d_in[6];
  const float* fc1_w  = (const float*)d_in[7];
  const float* fc1_b  = (const float*)d_in[8];
  const float* fc2_w  = (const float*)d_in[9];
  const float* fc2_b  = (const float*)d_in[10];
  const float* mean_w = (const float*)d_in[11];
  const float* mean_b = (const float*)d_in[12];
  const float* lstd   = (const float*)d_in[13];
  float* out = (float*)d_out;

  // workspace: gx [0,32MB) (reused as h1/h2), h_hist [32MB, 40.4MB)
  float* gx = (float*)d_ws;
  float* h_hist = gx + (size_t)T_SEQ * G4;
  float* h1 = gx;
  float* h2 = gx + (size_t)T_SEQ * H;

  init_k<<<dim3((T_SEQ + 1) * H / 256), 256, 0, stream>>>(h0, h_hist);
  gemm_bias_k<false, true><<<dim3(G4 / BN, T_SEQ / BM), 256, 0, stream>>>(
      x, w_ih, b_ih, b_hh, gx, T_SEQ, G4, K_IN);
  lstm_k<<<dim3(NWG), NTHR, 0, stream>>>(gx, w_hh, c0, h_hist, out);
  gemm_bias_k<true, false><<<dim3(H / BN, T_SEQ / BM), 256, 0, stream>>>(
      h_hist + H, fc1_w, fc1_b, nullptr, h1, T_SEQ, H, H);
  gemm_bias_k<true, false><<<dim3(H / BN, T_SEQ / BM), 256, 0, stream>>>(
      h1, fc2_w, fc2_b, nullptr, h2, T_SEQ, H, H);
  head_k<<<dim3(T_SEQ), 256, 0, stream>>>(h2, mean_w, mean_b, lstd, out);
}

// Round 6
// 3837.387 us; speedup vs baseline: 1.0367x; 1.0367x over previous
//
#include <hip/hip_runtime.h>
#include <stdint.h>

// ActuatorPolicyNet: x[2048,512] -> LSTM(H=1024) -> fc1 -> fc2 -> mean head.
// Phase B: persistent LSTM, 128 wg x 512 thr, unit-per-wave, register-resident
// w_hh. h exchange: sentinel-polled h-history with 2 REPLICAS (wg polls
// replica wg&1) to halve coherence-point hot-line queueing; producers store
// to both replicas from the redundant g==0 lanes (s=0,1) in parallel.

#define T_SEQ 2048
#define H 1024
#define G4 4096
#define K_IN 512
#define SENT 0x7FC0DEADu    // NaN bit pattern; real h values are never NaN
#define NREP 2
#define RSTRIDE ((T_SEQ + 1) * H)

__device__ __forceinline__ float sigmoidf_(float x) { return 1.0f / (1.0f + __expf(-x)); }
__device__ __forceinline__ float tanhf_(float x) { return 1.0f - 2.0f / (1.0f + __expf(2.0f * x)); }

// 16-B coherent poll load (reads at the device coherence point: sc0 sc1)
__device__ __forceinline__ uint4 poll_load16(const uint4* p) {
  uint4 v;
  asm volatile("global_load_dwordx4 %0, %1, off sc0 sc1\n\ts_waitcnt vmcnt(0)"
               : "=v"(v) : "v"(p) : "memory");
  return v;
}

// ---------------- init: both replicas: row0 = h0, rows 1..2048 = sentinel ----------------
__global__ void init_k(const float* __restrict__ h0, float* __restrict__ h_hist) {
  int idx = blockIdx.x * blockDim.x + threadIdx.x;
  if (idx >= NREP * RSTRIDE) return;
  int k = idx % RSTRIDE;  // position within replica
  if (k < H) {
    h_hist[idx] = h0[k];
  } else {
    ((unsigned*)h_hist)[idx] = SENT;
  }
}

// ---------------- generic fp32 GEMM: C = act(A[M,K] @ Bw[N,K]^T + b1 (+ b2)) ----------------
#define BM 64
#define BN 64
#define BK 32
#define LDT 68

template <bool RELU, bool HASB2>
__global__ __launch_bounds__(256) void gemm_bias_k(
    const float* __restrict__ A, const float* __restrict__ Bw,
    const float* __restrict__ b1, const float* __restrict__ b2,
    float* __restrict__ C, int M, int N, int K) {
  __shared__ float As[BK][LDT];
  __shared__ float Bs[BK][LDT];
  const int tid = threadIdx.x;
  const int m0 = blockIdx.y * BM;
  const int n0 = blockIdx.x * BN;
  const int tx = tid & 15, ty = tid >> 4;
  const int srow = tid >> 2;
  const int skq = tid & 3;

  float acc[4][4];
#pragma unroll
  for (int i = 0; i < 4; i++)
#pragma unroll
    for (int j = 0; j < 4; j++) acc[i][j] = 0.f;

  const float* Arow = A + (size_t)(m0 + srow) * K;
  const float* Brow = Bw + (size_t)(n0 + srow) * K;

  for (int k0 = 0; k0 < K; k0 += BK) {
    float4 a0 = *(const float4*)(Arow + k0 + skq * 8);
    float4 a1 = *(const float4*)(Arow + k0 + skq * 8 + 4);
    float4 c0_ = *(const float4*)(Brow + k0 + skq * 8);
    float4 c1_ = *(const float4*)(Brow + k0 + skq * 8 + 4);
    __syncthreads();
    const int kb = skq * 8;
    As[kb + 0][srow] = a0.x; As[kb + 1][srow] = a0.y; As[kb + 2][srow] = a0.z; As[kb + 3][srow] = a0.w;
    As[kb + 4][srow] = a1.x; As[kb + 5][srow] = a1.y; As[kb + 6][srow] = a1.z; As[kb + 7][srow] = a1.w;
    Bs[kb + 0][srow] = c0_.x; Bs[kb + 1][srow] = c0_.y; Bs[kb + 2][srow] = c0_.z; Bs[kb + 3][srow] = c0_.w;
    Bs[kb + 4][srow] = c1_.x; Bs[kb + 5][srow] = c1_.y; Bs[kb + 6][srow] = c1_.z; Bs[kb + 7][srow] = c1_.w;
    __syncthreads();
#pragma unroll
    for (int kk = 0; kk < BK; kk++) {
      float av[4], bv[4];
      *(float4*)av = *(const float4*)&As[kk][ty * 4];
      *(float4*)bv = *(const float4*)&Bs[kk][tx * 4];
#pragma unroll
      for (int i = 0; i < 4; i++)
#pragma unroll
        for (int j = 0; j < 4; j++) acc[i][j] = fmaf(av[i], bv[j], acc[i][j]);
    }
  }

  float bb[4];
#pragma unroll
  for (int j = 0; j < 4; j++) {
    bb[j] = b1[n0 + tx * 4 + j];
    if (HASB2) bb[j] += b2[n0 + tx * 4 + j];
  }
#pragma unroll
  for (int i = 0; i < 4; i++) {
    float4 o;
    float* op = (float*)&o;
#pragma unroll
    for (int j = 0; j < 4; j++) {
      float v = acc[i][j] + bb[j];
      op[j] = RELU ? fmaxf(v, 0.f) : v;
    }
    *(float4*)&C[(size_t)(m0 + ty * 4 + i) * N + n0 + tx * 4] = o;
  }
}

// ---------------- persistent LSTM recurrence ----------------
// 128 wgs x 512 thr (8 waves). wg owns 8 units; wave owns 1 unit.
// Lane = s*4+g (g=gate i,f,g,o; s=64-wide k-segment). Each lane holds
// w_hh[g*1024+unit][s*64..+64) in 16 named float4 values (component-wise
// asm pins; waves_per_eu(2,2) keeps the 256-VGPR budget -> resident).
// Exchange: g==0 lanes s=0,1 store hn to replicas 0,1; wg polls replica wg&1
// continuously (no sleep) with one dwordx4 sc0/sc1 load per poller.
#define NWG 128
#define NTHR 512
#define HPAD 68

#define PIN4(V) asm volatile("" : "+v"((V).x), "+v"((V).y), "+v"((V).z), "+v"((V).w))

__global__ __attribute__((amdgpu_waves_per_eu(2, 2))) __launch_bounds__(NTHR)
void lstm_k(
    const float* __restrict__ gx, const float* __restrict__ w_hh,
    const float* __restrict__ c0, float* __restrict__ h_hist,
    float* __restrict__ out) {
  unsigned* h_u = (unsigned*)h_hist;
  __shared__ float hbuf[2][16 * HPAD];
  const int tid = threadIdx.x;
  const int wg = blockIdx.x;
  const int wave = tid >> 6, lane = tid & 63;
  const int g = lane & 3;        // gate: 0=i 1=f 2=g 3=o
  const int s = lane >> 2;       // k-segment (0..15), 64 values each
  const int unit = wg * 8 + wave;
  const int grow = g * 1024 + unit;

  // preload weights into 16 named float4 SSA values (no array -> no alloca)
  const float* wp = w_hh + (size_t)grow * H + s * 64;
  float4 w0 = *(const float4*)(wp + 0),  w1 = *(const float4*)(wp + 4);
  float4 w2 = *(const float4*)(wp + 8),  w3 = *(const float4*)(wp + 12);
  float4 w4 = *(const float4*)(wp + 16), w5 = *(const float4*)(wp + 20);
  float4 w6 = *(const float4*)(wp + 24), w7 = *(const float4*)(wp + 28);
  float4 w8 = *(const float4*)(wp + 32), w9 = *(const float4*)(wp + 36);
  float4 wA = *(const float4*)(wp + 40), wB = *(const float4*)(wp + 44);
  float4 wC = *(const float4*)(wp + 48), wD = *(const float4*)(wp + 52);
  float4 wE = *(const float4*)(wp + 56), wF = *(const float4*)(wp + 60);
  PIN4(w0); PIN4(w1); PIN4(w2); PIN4(w3);
  PIN4(w4); PIN4(w5); PIN4(w6); PIN4(w7);
  PIN4(w8); PIN4(w9); PIN4(wA); PIN4(wB);
  PIN4(wC); PIN4(wD); PIN4(wE); PIN4(wF);

  float c = c0[unit];  // meaningful in g==0 lanes only

  const bool poller = tid < 256;
  const int stage_idx = 4 * tid + (tid >> 4) * 4;  // padded LDS slot
  unsigned* poll_base = h_u + (size_t)(wg & 1) * RSTRIDE;  // this wg's replica

  for (int t = 0; t < T_SEQ; t++) {
    const int buf = t & 1;
    // prefetch this step's gx so its latency overlaps the poll
    float gxv = gx[(size_t)t * G4 + grow];
    asm volatile("" : "+v"(gxv));

    if (poller) {
      const uint4* src = (const uint4*)(poll_base + (size_t)t * H) + tid;
      uint4 v = poll_load16(src);
      while (v.x == SENT || v.y == SENT || v.z == SENT || v.w == SENT)
        v = poll_load16(src);
      float4 f;
      f.x = __uint_as_float(v.x); f.y = __uint_as_float(v.y);
      f.z = __uint_as_float(v.z); f.w = __uint_as_float(v.w);
      *(float4*)&hbuf[buf][stage_idx] = f;
    }
    __syncthreads();  // single barrier per step (double-buffered hbuf)

    // 64 MACs, 4 accumulators, weights from named regs
    float acc0 = 0.f, acc1 = 0.f, acc2 = 0.f, acc3 = 0.f;
    const float* hs = &hbuf[buf][s * HPAD];
#define MAC(J, WV)                                  \
  {                                                 \
    float4 hv = *(const float4*)(hs + (J) * 4);     \
    acc0 = fmaf((WV).x, hv.x, acc0);                \
    acc1 = fmaf((WV).y, hv.y, acc1);                \
    acc2 = fmaf((WV).z, hv.z, acc2);                \
    acc3 = fmaf((WV).w, hv.w, acc3);                \
  }
    MAC(0, w0) MAC(1, w1) MAC(2, w2) MAC(3, w3)
    MAC(4, w4) MAC(5, w5) MAC(6, w6) MAC(7, w7)
    MAC(8, w8) MAC(9, w9) MAC(10, wA) MAC(11, wB)
    MAC(12, wC) MAC(13, wD) MAC(14, wE) MAC(15, wF)
#undef MAC
    float accv = (acc0 + acc1) + (acc2 + acc3);
    // reduce over the 16 k-segments (lane bits 2..5)
    accv += __shfl_xor(accv, 4);
    accv += __shfl_xor(accv, 8);
    accv += __shfl_xor(accv, 16);
    accv += __shfl_xor(accv, 32);
    float pre = accv + gxv;
    float act = (g == 2) ? tanhf_(pre) : sigmoidf_(pre);
    // gather gates (combination valid in g==0 lanes; independent shfls)
    float b1v = __shfl_xor(act, 1);
    float b2v = __shfl_xor(act, 2);
    float b3v = __shfl_xor(act, 3);
    c = fmaf(b1v, c, act * b2v);  // f*c + i*g   (g==0 lanes)
    float hn = b3v * tanhf_(c);   // o*tanh(c)
    // g==0 lanes s=0,1 each store to one replica (parallel, no serialization)
    if (g == 0 && s < NREP) {
      __hip_atomic_store(&h_u[(size_t)s * RSTRIDE + (size_t)(t + 1) * H + unit],
                         __float_as_uint(hn), __ATOMIC_RELAXED,
                         __HIP_MEMORY_SCOPE_AGENT);
      if (t == T_SEQ - 1 && s == 0) {
        out[16384 + unit] = hn;  // hT
        out[17408 + unit] = c;   // cT
      }
    }
  }
}

// ---------------- head: action_mean + log_std broadcast ----------------
__global__ __launch_bounds__(256) void head_k(
    const float* __restrict__ h2, const float* __restrict__ mean_w,
    const float* __restrict__ mean_b, const float* __restrict__ log_std,
    float* __restrict__ out) {
  const int t = blockIdx.x;
  const int tid = threadIdx.x;
  const int wave = tid >> 6, lane = tid & 63;  // wave = output index (OUT=4)
  const float* hr = h2 + (size_t)t * H;
  const float* wr = mean_w + (size_t)wave * H;
  float s = 0.f;
#pragma unroll
  for (int j = 0; j < 16; j++) s = fmaf(hr[lane + j * 64], wr[lane + j * 64], s);
#pragma unroll
  for (int off = 32; off > 0; off >>= 1) s += __shfl_down(s, off);
  if (lane == 0) out[t * 4 + wave] = s + mean_b[wave];
  if (tid < 4) out[8192 + t * 4 + tid] = log_std[tid];
}

extern "C" void kernel_launch(void* const* d_in, const int* in_sizes, int n_in,
                              void* d_out, int out_size, void* d_ws, size_t ws_size,
                              hipStream_t stream) {
  const float* x      = (const float*)d_in[0];
  const float* h0     = (const float*)d_in[1];
  const float* c0     = (const float*)d_in[2];
  const float* w_ih   = (const float*)d_in[3];
  const float* w_hh   = (const float*)d_in[4];
  const float* b_ih   = (const float*)d_in[5];
  const float* b_hh   = (const float*)d_in[6];
  const float* fc1_w  = (const float*)d_in[7];
  const float* fc1_b  = (const float*)d_in[8];
  const float* fc2_w  = (const float*)d_in[9];
  const float* fc2_b  = (const float*)d_in[10];
  const float* mean_w = (const float*)d_in[11];
  const float* mean_b = (const float*)d_in[12];
  const float* lstd   = (const float*)d_in[13];
  float* out = (float*)d_out;

  // workspace (~48.8 MB): gx [0,32MB) (reused as h1/h2), then 2 h_hist replicas
  float* gx = (float*)d_ws;
  float* h_hist = gx + (size_t)T_SEQ * G4;
  float* h1 = gx;
  float* h2 = gx + (size_t)T_SEQ * H;

  init_k<<<dim3((NREP * RSTRIDE + 255) / 256), 256, 0, stream>>>(h0, h_hist);
  gemm_bias_k<false, true><<<dim3(G4 / BN, T_SEQ / BM), 256, 0, stream>>>(
      x, w_ih, b_ih, b_hh, gx, T_SEQ, G4, K_IN);
  lstm_k<<<dim3(NWG), NTHR, 0, stream>>>(gx, w_hh, c0, h_hist, out);
  gemm_bias_k<true, false><<<dim3(H / BN, T_SEQ / BM), 256, 0, stream>>>(
      h_hist + H, fc1_w, fc1_b, nullptr, h1, T_SEQ, H, H);  // ys from replica 0
  gemm_bias_k<true, false><<<dim3(H / BN, T_SEQ / BM), 256, 0, stream>>>(
      h1, fc2_w, fc2_b, nullptr, h2, T_SEQ, H, H);
  head_k<<<dim3(T_SEQ), 256, 0, stream>>>(h2, mean_w, mean_b, lstd, out);
}